// Round 8
// baseline (461.083 us; speedup 1.0000x reference)
//
#include <hip/hip_runtime.h>
#include <hip/hip_fp16.h>

#define IN_FEAT 256
#define OUT_FEAT 128

typedef _Float16 half8 __attribute__((ext_vector_type(8)));
typedef _Float16 half4 __attribute__((ext_vector_type(4)));
typedef float    f32x4 __attribute__((ext_vector_type(4)));

#define WT_BYTES (OUT_FEAT * IN_FEAT * 2)   // 64 KB fp16 W^T image

// ---------------------------------------------------------------------------
// wprep: W[256,128] fp32 -> W^T[col][k] fp16, XOR-swizzled exactly as the
// gemm LDS image (byte = col*512 + k*2, ^ (col&7)<<4).
// ---------------------------------------------------------------------------
__global__ __launch_bounds__(256) void wprep_kernel(
    const float* __restrict__ W, char* __restrict__ wt)
{
    int t   = blockIdx.x * blockDim.x + threadIdx.x;   // 0..16383
    int col = t & 127;
    int k   = (t >> 7) * 2;                            // even k
    _Float16 h0 = (_Float16)W[(size_t)k       * OUT_FEAT + col];
    _Float16 h1 = (_Float16)W[(size_t)(k + 1) * OUT_FEAT + col];
    int byte = col * 512 + k * 2;
    byte ^= (col & 7) << 4;
    unsigned short u0, u1;
    __builtin_memcpy(&u0, &h0, 2);
    __builtin_memcpy(&u1, &h1, 2);
    *(unsigned int*)(wt + byte) = (unsigned int)u0 | ((unsigned int)u1 << 16);
}

// ---------------------------------------------------------------------------
// GEMM via f16 MFMA (unchanged — byte-identical for A/B purity).
// ---------------------------------------------------------------------------
#define GBM 128
#define GT  512

__global__ __launch_bounds__(GT, 1) void gemm_mfma_kernel(
    const float* __restrict__ A, const char* __restrict__ wt,
    float* __restrict__ C, __half* __restrict__ Ch, int M, int writeHalf)
{
    __shared__ _Float16 sA[GBM * IN_FEAT];      // [row][k], swizzled
    __shared__ _Float16 sW[OUT_FEAT * IN_FEAT]; // [col][k], swizzled

    const int t    = threadIdx.x;
    const int row0 = blockIdx.x * GBM;

    {
        const int row = t >> 2;
        const int kq  = t & 3;
        int grow = row0 + row; if (grow >= M) grow = M - 1;
        const float* Ap = &A[(size_t)grow * IN_FEAT];
        #pragma unroll
        for (int i = 0; i < 8; ++i) {
            int k = kq * 8 + i * 32;
            float4 a0 = *(const float4*)(Ap + k);
            float4 a1 = *(const float4*)(Ap + k + 4);
            half8 h;
            h[0]=(_Float16)a0.x; h[1]=(_Float16)a0.y; h[2]=(_Float16)a0.z; h[3]=(_Float16)a0.w;
            h[4]=(_Float16)a1.x; h[5]=(_Float16)a1.y; h[6]=(_Float16)a1.z; h[7]=(_Float16)a1.w;
            int byte = row * 512 + k * 2;
            byte ^= (row & 7) << 4;
            *(half8*)((char*)sA + byte) = h;
        }
    }
    {
        const float4* src = (const float4*)wt;
        float4*       dst = (float4*)sW;
        #pragma unroll
        for (int i = 0; i < 8; ++i) dst[t + GT * i] = src[t + GT * i];
    }
    __syncthreads();

    const int wid  = t >> 6;
    const int lane = t & 63;
    const int rowBase = wid * 16;
    const int fr = lane & 15;
    const int fk = lane >> 4;

    f32x4 acc[8];
    #pragma unroll
    for (int nt = 0; nt < 8; ++nt) acc[nt] = (f32x4){0.f, 0.f, 0.f, 0.f};

    #pragma unroll
    for (int ks = 0; ks < 8; ++ks) {
        const int arow  = rowBase + fr;
        int abyte = arow * 512 + ks * 64 + fk * 16;
        abyte ^= (arow & 7) << 4;
        half8 af = *(const half8*)((const char*)sA + abyte);
        #pragma unroll
        for (int nt = 0; nt < 8; ++nt) {
            const int col = nt * 16 + fr;
            int bbyte = col * 512 + ks * 64 + fk * 16;
            bbyte ^= (col & 7) << 4;
            half8 bf = *(const half8*)((const char*)sW + bbyte);
            acc[nt] = __builtin_amdgcn_mfma_f32_16x16x32_f16(bf, af, acc[nt], 0, 0, 0);
        }
    }

    const int grow = row0 + rowBase + fr;
    if (grow < M) {
        #pragma unroll
        for (int nt = 0; nt < 8; ++nt) {
            const int col0 = nt * 16 + fk * 4;
            float4 o = {acc[nt][0], acc[nt][1], acc[nt][2], acc[nt][3]};
            *(float4*)&C[(size_t)grow * OUT_FEAT + col0] = o;
            if (writeHalf) {
                half4 h = {(_Float16)o.x, (_Float16)o.y, (_Float16)o.z, (_Float16)o.w};
                *(half4*)&Ch[(size_t)grow * OUT_FEAT + col0] = h;
            }
        }
    }
}

// ---------------------------------------------------------------------------
// zero-fill x
// ---------------------------------------------------------------------------
__global__ void zero_kernel(float4* __restrict__ p, int n4)
{
    int i      = blockIdx.x * blockDim.x + threadIdx.x;
    int stride = gridDim.x * blockDim.x;
    for (; i < n4; i += stride) p[i] = float4{0.f, 0.f, 0.f, 0.f};
}

// ---------------------------------------------------------------------------
// SpMM over sorted COO — pair-edge layout:
//  lane q=lane&31 owns 4 cols (half4 = 8B); hi=lane>>5 selects edge of pair.
//  One gather instruction moves 512B covering 2 edges (half VMEM instrs).
//  Flush combines halves via shfl_xor(32) then 32 lanes x 4 atomics
//  (still exactly 1 atomic per output col). Mid-pair row boundary handled
//  branchlessly with parity-masked fma. 16-pair (32-edge) gather batches.
// ---------------------------------------------------------------------------
#define EPB 512
#define EPW 128
#define PPB 16   // pairs per batch

template<int USE_H>
__global__ __launch_bounds__(256) void spmm_kernel(
    const int*   __restrict__ erow, const int* __restrict__ ecol,
    const float* __restrict__ eval, const float* __restrict__ femb,
    const __half* __restrict__ fembh, float* __restrict__ x, int E)
{
    __shared__ int   s_row[EPB];
    __shared__ int   s_col[EPB];
    __shared__ float s_val[EPB];

    const int blockBase = blockIdx.x * EPB;

    #pragma unroll
    for (int i = 0; i < 2; ++i) {
        int li = threadIdx.x + i * 256;
        int e  = blockBase + li;
        if (e < E) {
            s_row[li] = __builtin_nontemporal_load(&erow[e]);
            s_col[li] = __builtin_nontemporal_load(&ecol[e]);
            s_val[li] = __builtin_nontemporal_load(&eval[e]);
        }
    }
    __syncthreads();

    const int wave = threadIdx.x >> 6;
    const int lane = threadIdx.x & 63;
    const int q    = lane & 31;
    const int hi   = lane >> 5;          // 0 = even edge of pair, 1 = odd
    const int c0   = q * 4;              // this lane's 4 feature cols

    const int w0 = wave * EPW;
    const int g0 = blockBase + w0;
    if (g0 >= E) return;
    const int n = min(EPW, E - g0);

    float4 acc = {0.f, 0.f, 0.f, 0.f};
    int cur = s_row[w0];

    auto flushAcc = [&](int row) {
        float4 o;
        o.x = __shfl_xor(acc.x, 32);
        o.y = __shfl_xor(acc.y, 32);
        o.z = __shfl_xor(acc.z, 32);
        o.w = __shfl_xor(acc.w, 32);
        if (lane < 32) {
            float* xp = &x[(size_t)row * OUT_FEAT + c0];
            atomicAdd(xp + 0, acc.x + o.x);
            atomicAdd(xp + 1, acc.y + o.y);
            atomicAdd(xp + 2, acc.z + o.z);
            atomicAdd(xp + 3, acc.w + o.w);
        }
        acc.x = 0.f; acc.y = 0.f; acc.z = 0.f; acc.w = 0.f;
    };

    auto consumePair = [&](int p, float4 f, bool hasOdd) {
        int   r0 = s_row[p];
        int   r1 = hasOdd ? s_row[p + 1] : r0;
        float v  = (hi && !hasOdd) ? 0.f : s_val[p + (hasOdd ? hi : 0)];
        if (r0 != cur) { flushAcc(cur); cur = r0; }
        if (r1 == r0) {
            acc.x = fmaf(v, f.x, acc.x);
            acc.y = fmaf(v, f.y, acc.y);
            acc.z = fmaf(v, f.z, acc.z);
            acc.w = fmaf(v, f.w, acc.w);
        } else {
            // row boundary inside the pair: parity-masked double add
            float v0 = hi ? 0.f : v;
            acc.x = fmaf(v0, f.x, acc.x);
            acc.y = fmaf(v0, f.y, acc.y);
            acc.z = fmaf(v0, f.z, acc.z);
            acc.w = fmaf(v0, f.w, acc.w);
            flushAcc(cur);
            cur = r1;
            float v1 = hi ? v : 0.f;
            acc.x = fmaf(v1, f.x, acc.x);
            acc.y = fmaf(v1, f.y, acc.y);
            acc.z = fmaf(v1, f.z, acc.z);
            acc.w = fmaf(v1, f.w, acc.w);
        }
    };

    if (n == EPW) {
        #pragma unroll 1
        for (int base = 0; base < EPW; base += 2 * PPB) {
            // issue all 16 pair-gathers (512B each) before consuming
            half4  hb[PPB];
            float4 fb[PPB];
            if constexpr (USE_H) {
                #pragma unroll
                for (int i = 0; i < PPB; ++i) {
                    int c = s_col[w0 + base + 2 * i + hi];
                    hb[i] = *(const half4*)&fembh[(size_t)c * OUT_FEAT + c0];
                }
            } else {
                #pragma unroll
                for (int i = 0; i < PPB; ++i) {
                    int c = s_col[w0 + base + 2 * i + hi];
                    fb[i] = *(const float4*)&femb[(size_t)c * OUT_FEAT + c0];
                }
            }
            #pragma unroll
            for (int i = 0; i < PPB; ++i) {
                float4 f;
                if constexpr (USE_H) {
                    f.x = (float)hb[i][0]; f.y = (float)hb[i][1];
                    f.z = (float)hb[i][2]; f.w = (float)hb[i][3];
                } else f = fb[i];
                consumePair(w0 + base + 2 * i, f, true);
            }
        }
    } else {
        for (int base = 0; base < n; base += 2) {
            bool hasOdd = (base + 1) < n;
            int  p  = w0 + base;
            int  pe = p + (hasOdd ? hi : 0);
            int  c  = s_col[pe];
            float4 f;
            if constexpr (USE_H) {
                half4 h = *(const half4*)&fembh[(size_t)c * OUT_FEAT + c0];
                f.x = (float)h[0]; f.y = (float)h[1];
                f.z = (float)h[2]; f.w = (float)h[3];
            } else {
                f = *(const float4*)&femb[(size_t)c * OUT_FEAT + c0];
            }
            consumePair(p, f, hasOdd);
        }
    }
    flushAcc(cur);
}

// ---------------------------------------------------------------------------
extern "C" void kernel_launch(void* const* d_in, const int* in_sizes, int n_in,
                              void* d_out, int out_size, void* d_ws, size_t ws_size,
                              hipStream_t stream)
{
    const float* feat = (const float*)d_in[0];
    const int*   erow = (const int*)  d_in[1];
    const int*   ecol = (const int*)  d_in[2];
    const float* eval = (const float*)d_in[3];
    const float* W    = (const float*)d_in[4];

    const int M = in_sizes[0] / IN_FEAT;   // 100000
    const int E = in_sizes[1];             // 3200000

    float*  femb  = (float*)d_out;
    float*  x     = femb + (size_t)M * OUT_FEAT;
    char*   wt    = (char*)d_ws;                       // 64 KB W^T image
    __half* fembh = (__half*)((char*)d_ws + WT_BYTES); // fp16 femb copy

    const size_t needH = (size_t)WT_BYTES + (size_t)M * OUT_FEAT * sizeof(__half);
    const int useH = (ws_size >= needH) ? 1 : 0;

    wprep_kernel<<<64, 256, 0, stream>>>(W, wt);

    gemm_mfma_kernel<<<(M + GBM - 1) / GBM, GT, 0, stream>>>(feat, wt, femb, fembh, M, useH);

    zero_kernel<<<2048, 256, 0, stream>>>((float4*)x, (M * OUT_FEAT) / 4);

    int nblk = (E + EPB - 1) / EPB;
    if (useH) spmm_kernel<1><<<nblk, 256, 0, stream>>>(erow, ecol, eval, femb, fembh, x, E);
    else      spmm_kernel<0><<<nblk, 256, 0, stream>>>(erow, ecol, eval, femb, fembh, x, E);
}

// Round 11
// 363.044 us; speedup vs baseline: 1.2700x; 1.2700x over previous
//
#include <hip/hip_runtime.h>
#include <hip/hip_fp16.h>

#define IN_FEAT 256
#define OUT_FEAT 128

typedef _Float16 half8 __attribute__((ext_vector_type(8)));
typedef _Float16 half4 __attribute__((ext_vector_type(4)));
typedef float    f32x4 __attribute__((ext_vector_type(4)));

#define WT_BYTES (OUT_FEAT * IN_FEAT * 2)   // 64 KB fp16 W^T image

// ---------------------------------------------------------------------------
// wprep: W[256,128] fp32 -> W^T[col][k] fp16, XOR-swizzled as the gemm image.
// ---------------------------------------------------------------------------
__global__ __launch_bounds__(256) void wprep_kernel(
    const float* __restrict__ W, char* __restrict__ wt)
{
    int t   = blockIdx.x * blockDim.x + threadIdx.x;   // 0..16383
    int col = t & 127;
    int k   = (t >> 7) * 2;                            // even k
    _Float16 h0 = (_Float16)W[(size_t)k       * OUT_FEAT + col];
    _Float16 h1 = (_Float16)W[(size_t)(k + 1) * OUT_FEAT + col];
    int byte = col * 512 + k * 2;
    byte ^= (col & 7) << 4;
    unsigned short u0, u1;
    __builtin_memcpy(&u0, &h0, 2);
    __builtin_memcpy(&u1, &h1, 2);
    *(unsigned int*)(wt + byte) = (unsigned int)u0 | ((unsigned int)u1 << 16);
}

// ---------------------------------------------------------------------------
// GEMM via f16 MFMA (unchanged — byte-identical for A/B purity).
// ---------------------------------------------------------------------------
#define GBM 128
#define GT  512

__global__ __launch_bounds__(GT, 1) void gemm_mfma_kernel(
    const float* __restrict__ A, const char* __restrict__ wt,
    float* __restrict__ C, __half* __restrict__ Ch, int M, int writeHalf)
{
    __shared__ _Float16 sA[GBM * IN_FEAT];      // [row][k], swizzled
    __shared__ _Float16 sW[OUT_FEAT * IN_FEAT]; // [col][k], swizzled

    const int t    = threadIdx.x;
    const int row0 = blockIdx.x * GBM;

    {
        const int row = t >> 2;
        const int kq  = t & 3;
        int grow = row0 + row; if (grow >= M) grow = M - 1;
        const float* Ap = &A[(size_t)grow * IN_FEAT];
        #pragma unroll
        for (int i = 0; i < 8; ++i) {
            int k = kq * 8 + i * 32;
            float4 a0 = *(const float4*)(Ap + k);
            float4 a1 = *(const float4*)(Ap + k + 4);
            half8 h;
            h[0]=(_Float16)a0.x; h[1]=(_Float16)a0.y; h[2]=(_Float16)a0.z; h[3]=(_Float16)a0.w;
            h[4]=(_Float16)a1.x; h[5]=(_Float16)a1.y; h[6]=(_Float16)a1.z; h[7]=(_Float16)a1.w;
            int byte = row * 512 + k * 2;
            byte ^= (row & 7) << 4;
            *(half8*)((char*)sA + byte) = h;
        }
    }
    {
        const float4* src = (const float4*)wt;
        float4*       dst = (float4*)sW;
        #pragma unroll
        for (int i = 0; i < 8; ++i) dst[t + GT * i] = src[t + GT * i];
    }
    __syncthreads();

    const int wid  = t >> 6;
    const int lane = t & 63;
    const int rowBase = wid * 16;
    const int fr = lane & 15;
    const int fk = lane >> 4;

    f32x4 acc[8];
    #pragma unroll
    for (int nt = 0; nt < 8; ++nt) acc[nt] = (f32x4){0.f, 0.f, 0.f, 0.f};

    #pragma unroll
    for (int ks = 0; ks < 8; ++ks) {
        const int arow  = rowBase + fr;
        int abyte = arow * 512 + ks * 64 + fk * 16;
        abyte ^= (arow & 7) << 4;
        half8 af = *(const half8*)((const char*)sA + abyte);
        #pragma unroll
        for (int nt = 0; nt < 8; ++nt) {
            const int col = nt * 16 + fr;
            int bbyte = col * 512 + ks * 64 + fk * 16;
            bbyte ^= (col & 7) << 4;
            half8 bf = *(const half8*)((const char*)sW + bbyte);
            acc[nt] = __builtin_amdgcn_mfma_f32_16x16x32_f16(bf, af, acc[nt], 0, 0, 0);
        }
    }

    const int grow = row0 + rowBase + fr;
    if (grow < M) {
        #pragma unroll
        for (int nt = 0; nt < 8; ++nt) {
            const int col0 = nt * 16 + fk * 4;
            float4 o = {acc[nt][0], acc[nt][1], acc[nt][2], acc[nt][3]};
            *(float4*)&C[(size_t)grow * OUT_FEAT + col0] = o;
            if (writeHalf) {
                half4 h = {(_Float16)o.x, (_Float16)o.y, (_Float16)o.z, (_Float16)o.w};
                *(half4*)&Ch[(size_t)grow * OUT_FEAT + col0] = h;
            }
        }
    }
}

// ---------------------------------------------------------------------------
// zero-fill x
// ---------------------------------------------------------------------------
__global__ void zero_kernel(float4* __restrict__ p, int n4)
{
    int i      = blockIdx.x * blockDim.x + threadIdx.x;
    int stride = gridDim.x * blockDim.x;
    for (; i < n4; i += stride) p[i] = float4{0.f, 0.f, 0.f, 0.f};
}

// ---------------------------------------------------------------------------
// SpMM over sorted COO — R6 structure (lane owns 2 cols, half2 gather,
// 2-atomic contiguous flush) + explicit double-buffered gather pipeline:
// batch b+1's 16 gathers are issued into the alternate register buffer
// BEFORE consuming batch b; sched_barrier(0) pins the issue point so the
// compiler cannot sink loads into the consume loop (which it provably did
// before: VGPR_Count=24 < the 16 buffer regs). Latency paid once per wave,
// not once per batch.
// ---------------------------------------------------------------------------
#define EPB 512
#define EPW 128
#define PF  16

template<int USE_H>
__global__ __launch_bounds__(256) void spmm_kernel(
    const int*   __restrict__ erow, const int* __restrict__ ecol,
    const float* __restrict__ eval, const float* __restrict__ femb,
    const __half* __restrict__ fembh, float* __restrict__ x, int E)
{
    __shared__ int   s_row[EPB];
    __shared__ int   s_col[EPB];
    __shared__ float s_val[EPB];

    const int blockBase = blockIdx.x * EPB;

    #pragma unroll
    for (int i = 0; i < 2; ++i) {
        int li = threadIdx.x + i * 256;
        int e  = blockBase + li;
        if (e < E) {
            s_row[li] = __builtin_nontemporal_load(&erow[e]);
            s_col[li] = __builtin_nontemporal_load(&ecol[e]);
            s_val[li] = __builtin_nontemporal_load(&eval[e]);
        }
    }
    __syncthreads();

    const int wave = threadIdx.x >> 6;
    const int lane = threadIdx.x & 63;
    const int j    = lane * 2;

    const int w0 = wave * EPW;
    const int g0 = blockBase + w0;
    if (g0 >= E) return;
    const int n = min(EPW, E - g0);

    float2 acc = {0.f, 0.f};
    int cur = s_row[w0];

    auto flush = [&](int row) {
        atomicAdd(&x[(size_t)row * OUT_FEAT + j],     acc.x);
        atomicAdd(&x[(size_t)row * OUT_FEAT + j + 1], acc.y);
        acc.x = 0.f; acc.y = 0.f;
    };

    if (n == EPW) {
        __half2 fA[PF], fB[PF];
        float2  gA[PF], gB[PF];

        auto issueH = [&](int base, __half2* f) {
            #pragma unroll
            for (int i = 0; i < PF; ++i) {
                int c = s_col[w0 + base + i];
                f[i] = *(const __half2*)&fembh[(size_t)c * OUT_FEAT + j];
            }
        };
        auto issueF = [&](int base, float2* f) {
            #pragma unroll
            for (int i = 0; i < PF; ++i) {
                int c = s_col[w0 + base + i];
                f[i] = *(const float2*)&femb[(size_t)c * OUT_FEAT + j];
            }
        };
        auto consumeH = [&](int base, const __half2* f) {
            #pragma unroll
            for (int i = 0; i < PF; ++i) {
                int r = s_row[w0 + base + i];
                if (r != cur) { flush(cur); cur = r; }
                float v = s_val[w0 + base + i];
                float2 fv = __half22float2(f[i]);
                acc.x = fmaf(v, fv.x, acc.x);
                acc.y = fmaf(v, fv.y, acc.y);
            }
        };
        auto consumeF = [&](int base, const float2* f) {
            #pragma unroll
            for (int i = 0; i < PF; ++i) {
                int r = s_row[w0 + base + i];
                if (r != cur) { flush(cur); cur = r; }
                float v = s_val[w0 + base + i];
                acc.x = fmaf(v, f[i].x, acc.x);
                acc.y = fmaf(v, f[i].y, acc.y);
            }
        };

        if constexpr (USE_H) {
            issueH(0, fA);
            __builtin_amdgcn_sched_barrier(0);
            #pragma unroll 1
            for (int base = 0; base < EPW; base += 2 * PF) {
                issueH(base + PF, fB);
                __builtin_amdgcn_sched_barrier(0);
                consumeH(base, fA);
                int nb = base + 2 * PF;
                if (nb < EPW) {
                    issueH(nb, fA);
                    __builtin_amdgcn_sched_barrier(0);
                }
                consumeH(base + PF, fB);
            }
        } else {
            issueF(0, gA);
            __builtin_amdgcn_sched_barrier(0);
            #pragma unroll 1
            for (int base = 0; base < EPW; base += 2 * PF) {
                issueF(base + PF, gB);
                __builtin_amdgcn_sched_barrier(0);
                consumeF(base, gA);
                int nb = base + 2 * PF;
                if (nb < EPW) {
                    issueF(nb, gA);
                    __builtin_amdgcn_sched_barrier(0);
                }
                consumeF(base + PF, gB);
            }
        }
    } else {
        for (int idx = 0; idx < n; ++idx) {
            int r = s_row[w0 + idx];
            if (r != cur) { flush(cur); cur = r; }
            int c = s_col[w0 + idx];
            float v = s_val[w0 + idx];
            float2 fv;
            if constexpr (USE_H) fv = __half22float2(*(const __half2*)&fembh[(size_t)c * OUT_FEAT + j]);
            else                 fv = *(const float2*)&femb[(size_t)c * OUT_FEAT + j];
            acc.x = fmaf(v, fv.x, acc.x);
            acc.y = fmaf(v, fv.y, acc.y);
        }
    }
    flush(cur);
}

// ---------------------------------------------------------------------------
extern "C" void kernel_launch(void* const* d_in, const int* in_sizes, int n_in,
                              void* d_out, int out_size, void* d_ws, size_t ws_size,
                              hipStream_t stream)
{
    const float* feat = (const float*)d_in[0];
    const int*   erow = (const int*)  d_in[1];
    const int*   ecol = (const int*)  d_in[2];
    const float* eval = (const float*)d_in[3];
    const float* W    = (const float*)d_in[4];

    const int M = in_sizes[0] / IN_FEAT;   // 100000
    const int E = in_sizes[1];             // 3200000

    float*  femb  = (float*)d_out;
    float*  x     = femb + (size_t)M * OUT_FEAT;
    char*   wt    = (char*)d_ws;                       // 64 KB W^T image
    __half* fembh = (__half*)((char*)d_ws + WT_BYTES); // fp16 femb copy

    const size_t needH = (size_t)WT_BYTES + (size_t)M * OUT_FEAT * sizeof(__half);
    const int useH = (ws_size >= needH) ? 1 : 0;

    wprep_kernel<<<64, 256, 0, stream>>>(W, wt);

    gemm_mfma_kernel<<<(M + GBM - 1) / GBM, GT, 0, stream>>>(feat, wt, femb, fembh, M, useH);

    zero_kernel<<<2048, 256, 0, stream>>>((float4*)x, (M * OUT_FEAT) / 4);

    int nblk = (E + EPB - 1) / EPB;
    if (useH) spmm_kernel<1><<<nblk, 256, 0, stream>>>(erow, ecol, eval, femb, fembh, x, E);
    else      spmm_kernel<0><<<nblk, 256, 0, stream>>>(erow, ecol, eval, femb, fembh, x, E);
}